// Round 1
// baseline (96.885 us; speedup 1.0000x reference)
//
#include <hip/hip_runtime.h>

#define TT 20
#define SS 256
#define PP 128
#define BB (SS * PP)
#define MLPD 1024
#define BN_EPS 1e-5f
#define THR_BITS 0x3D800000u  // bits of 0.0625f == 0.25^2

// ---------------- Kernel 1: collision flags, one block per scene ----------------
// 512 threads: thread handles ped i = tid&127, time-quarter q = tid>>7 (5 t's).
// Per pair: d2 computed with explicit rn ops (bit-identical to numpy's
// diff*diff then sum), then integer trick: u = bits(d2)-1; u==0xFFFFFFFF for
// d2==0 (self / exact-duplicate -> excluded, matching d==0 -> THR semantics);
// collision iff min u < THR_BITS-1 (exactly equivalent to sqrt(d2) < 0.25 after
// round-to-nearest — no representable d2 falls in the disagreement gap).
__global__ __launch_bounds__(512) void collide_kernel(
    const float* __restrict__ traj, unsigned* __restrict__ flags) {
  __shared__ float2 sp[TT * PP];     // 20 KB
  __shared__ unsigned red[512];
  const int s = blockIdx.x;
  const int tid = threadIdx.x;

  const float2* g = (const float2*)traj;  // (T, B) of float2
  for (int k = tid; k < TT * PP; k += 512) {
    int t = k >> 7;
    int ped = k & 127;
    sp[k] = g[(size_t)t * BB + s * PP + ped];
  }
  __syncthreads();

  const int i = tid & 127;
  const int q = tid >> 7;  // 0..3 -> t in [q*5, q*5+5)
  unsigned mn = 0xFFFFFFFFu;
#pragma unroll
  for (int tt = 0; tt < 5; ++tt) {
    const int t = q * 5 + tt;
    const float2 pi = sp[t * PP + i];
    const float xi = pi.x, yi = pi.y;
#pragma unroll 8
    for (int j = 0; j < PP; ++j) {
      float2 pj = sp[t * PP + j];  // wave-uniform address -> LDS broadcast
      float dx = __fsub_rn(xi, pj.x);
      float dy = __fsub_rn(yi, pj.y);
      float d2 = __fadd_rn(__fmul_rn(dx, dx), __fmul_rn(dy, dy));
      unsigned u = __float_as_uint(d2) - 1u;
      mn = (u < mn) ? u : mn;
    }
  }
  red[tid] = mn;
  __syncthreads();
  if (tid < 128) {
    unsigned m0 = red[tid];
    unsigned m1 = red[tid + 128];
    unsigned m2 = red[tid + 256];
    unsigned m3 = red[tid + 384];
    unsigned a = m0 < m1 ? m0 : m1;
    unsigned b = m2 < m3 ? m2 : m3;
    unsigned m = a < b ? a : b;
    flags[s * PP + tid] = (m < (THR_BITS - 1u)) ? 1u : 0u;  // 1 = collision
  }
}

// ---------------- Kernel 2: count + closed-form 2-row MLP -> two scalars ----------------
__global__ __launch_bounds__(1024) void mlp_kernel(
    const unsigned* __restrict__ flags,
    const float* __restrict__ W1, const float* __restrict__ b1,
    const float* __restrict__ g1, const float* __restrict__ beta1,
    const float* __restrict__ W2, const float* __restrict__ b2,
    const float* __restrict__ g2, const float* __restrict__ beta2,
    float* __restrict__ outvals) {
  __shared__ float red0[1024];
  __shared__ float red1[1024];
  __shared__ float sh_p;
  const int tid = threadIdx.x;

  // Count collisions (32768 flags, 8 x uint4 per thread)
  const uint4* f4 = (const uint4*)flags;
  unsigned cnt = 0;
#pragma unroll
  for (int k = 0; k < 8; ++k) {
    uint4 v = f4[tid + k * 1024];
    cnt += v.x + v.y + v.z + v.w;
  }
  red0[tid] = (float)cnt;
  __syncthreads();
  for (int off = 512; off > 0; off >>= 1) {
    if (tid < off) red0[tid] += red0[tid + off];
    __syncthreads();
  }
  if (tid == 0) {
    float ncoll = red0[0];
    sh_p = ((float)BB - ncoll) / (float)BB;  // fraction with reward == 1
  }
  __syncthreads();
  const float p = sh_p;

  // Layer 1 closed form per feature: x(r) = r*W1[k] + b1[k]
  // mean = b1 + p*W1, var = p(1-p)*W1^2
  float w = W1[tid], gg = g1[tid], bt = beta1[tid], w2 = W2[tid];
  float rs1 = rsqrtf(p * (1.0f - p) * w * w + BN_EPS);
  float h0 = fmaxf(gg * (-p * w) * rs1 + bt, 0.0f);         // r=0 row
  float h1 = fmaxf(gg * ((1.0f - p) * w) * rs1 + bt, 0.0f); // r=1 row
  red0[tid] = h0 * w2;
  red1[tid] = h1 * w2;
  __syncthreads();
  for (int off = 512; off > 0; off >>= 1) {
    if (tid < off) {
      red0[tid] += red0[tid + off];
      red1[tid] += red1[tid + off];
    }
    __syncthreads();
  }
  if (tid == 0) {
    float z0 = red0[0] + b2[0];
    float z1 = red1[0] + b2[0];
    float dz = z1 - z0;
    float rs2 = rsqrtf(p * (1.0f - p) * dz * dz + BN_EPS);
    float o0 = fmaxf(g2[0] * (p * (z0 - z1)) * rs2 + beta2[0], 0.0f);
    float o1 = fmaxf(g2[0] * ((1.0f - p) * dz) * rs2 + beta2[0], 0.0f);
    outvals[0] = o0;  // collided (reward 0)
    outvals[1] = o1;  // free     (reward 1)
  }
}

// ---------------- Kernel 3: scatter the two scalars ----------------
__global__ __launch_bounds__(256) void scatter_kernel(
    const unsigned* __restrict__ flags, const float* __restrict__ outvals,
    float* __restrict__ out) {
  int gid = blockIdx.x * 256 + threadIdx.x;
  float o0 = outvals[0];
  float o1 = outvals[1];
  out[gid] = flags[gid] ? o0 : o1;
}

extern "C" void kernel_launch(void* const* d_in, const int* in_sizes, int n_in,
                              void* d_out, int out_size, void* d_ws, size_t ws_size,
                              hipStream_t stream) {
  const float* traj = (const float*)d_in[0];
  // d_in[1] traj_rel: unused (stop_gradient + binary threshold kill it)
  // d_in[2] seq_start_end: fixed equal segments, structure hard-coded
  const float* W1 = (const float*)d_in[3];
  const float* b1 = (const float*)d_in[4];
  const float* g1 = (const float*)d_in[5];
  const float* beta1 = (const float*)d_in[6];
  const float* W2 = (const float*)d_in[7];
  const float* b2 = (const float*)d_in[8];
  const float* g2 = (const float*)d_in[9];
  const float* beta2 = (const float*)d_in[10];

  unsigned* flags = (unsigned*)d_ws;                       // 32768 * 4 B
  float* outvals = (float*)((char*)d_ws + BB * sizeof(unsigned));
  float* out = (float*)d_out;

  collide_kernel<<<SS, 512, 0, stream>>>(traj, flags);
  mlp_kernel<<<1, 1024, 0, stream>>>(flags, W1, b1, g1, beta1, W2, b2, g2,
                                     beta2, outvals);
  scatter_kernel<<<BB / 256, 256, 0, stream>>>(flags, outvals, out);
}